// Round 20
// baseline (120.726 us; speedup 1.0000x reference)
//
#include <hip/hip_runtime.h>
#include <hip/hip_bf16.h>
#include <stdint.h>

typedef __hip_bfloat16 bf16;
typedef __attribute__((ext_vector_type(8))) short short8;
typedef __attribute__((ext_vector_type(4))) float f32x4;
typedef __attribute__((ext_vector_type(16))) float f32x16;

#define MFMA16(A, B, C) __builtin_amdgcn_mfma_f32_16x16x32_bf16(A, B, C, 0, 0, 0)
#define MFMA32(A, B, C) __builtin_amdgcn_mfma_f32_32x32x16_bf16(A, B, C, 0, 0, 0)

// ---- constants ----
#define SB 2
#define SS 2048
#define SD 768
#define SH 12
#define SM (SB*SS)            // 4096 rows
#define BHSD (SB*SH*SS*64)    // 3145728 elems per Q/K/V
// (1/sqrt(64)) * log2(e) folded into Q at projection time -> attn works in exp2 domain
#define QSCALE 0.18033688011112042f

__device__ __forceinline__ void gload_lds16(const bf16* g, bf16* l) {
    __builtin_amdgcn_global_load_lds(
        (const __attribute__((address_space(1))) void*)(g),
        (__attribute__((address_space(3))) void*)(l),
        16, 0, 0);
}

// f32 pair -> packed bf16 (lo=a, hi=b)
__device__ __forceinline__ int cvtpk(float a, float b) {
    int r;
    asm("v_cvt_pk_bf16_f32 %0, %1, %2" : "=v"(r) : "v"(a), "v"(b));
    return r;
}
// a's lanes 32-63 <-> b's lanes 0-31
__device__ __forceinline__ void plswap(int& a, int& b) {
    asm("v_permlane32_swap_b32 %0, %1" : "+v"(a), "+v"(b));
}

// ---- workspace zero ----
__global__ void zero_ws(float4* __restrict__ p) {
    p[blockIdx.x * 256 + threadIdx.x] = make_float4(0.f, 0.f, 0.f, 0.f);
}

// ---- fused f32 -> bf16 convert for x + 4 weights ----
__global__ void cvt_all(const float4* __restrict__ x,  const float4* __restrict__ w0,
                        const float4* __restrict__ w1, const float4* __restrict__ w2,
                        const float4* __restrict__ w3,
                        uint64_t* __restrict__ xb, uint64_t* __restrict__ wqkv,
                        uint64_t* __restrict__ wob) {
    int bid = blockIdx.x;
    const float4* s; uint64_t* d; int base;
    if (bid < 3072) { s = x; d = xb; base = bid << 8; }
    else {
        int t = bid - 3072, seg = t / 576, li = t - seg * 576;
        s = (seg == 0) ? w0 : (seg == 1) ? w1 : (seg == 2) ? w2 : w3;
        d = (seg < 3) ? (wqkv + seg * 147456) : wob;
        base = li << 8;
    }
    int i = base + threadIdx.x;
    float4 v = s[i];
    union { bf16 h[4]; uint64_t u; } p;
    p.h[0] = __float2bfloat16(v.x);
    p.h[1] = __float2bfloat16(v.y);
    p.h[2] = __float2bfloat16(v.z);
    p.h[3] = __float2bfloat16(v.w);
    d[i] = p.u;
}

// ---- MFMA GEMM: Y = A[M,K] @ Bw[N,K]^T, 128x128 tile, BK=64 ----
template<int EPI>
__global__ __launch_bounds__(256) void gemm_bt(const bf16* __restrict__ A,
                                               const bf16* __restrict__ Bw,
                                               void* __restrict__ Out,
                                               int K) {
    __shared__ bf16 lA[128 * 64];
    __shared__ bf16 lB[128 * 64];
    const int tid  = threadIdx.x;
    const int lane = tid & 63;
    const int wid  = tid >> 6;
    const int wr = wid >> 1, wc = wid & 1;
    const int m0 = blockIdx.y * 128, n0 = blockIdx.x * 128;
    const int g = lane >> 4, l15 = lane & 15;
    const int srow = lane >> 3, slot = lane & 7;

    f32x4 acc[4][4] = {};

    for (int kt = 0; kt < K; kt += 64) {
        __syncthreads();
        #pragma unroll
        for (int p = 0; p < 4; ++p) {
            int c = wid * 4 + p;
            int row = c * 8 + srow;
            int colsw = (slot ^ (row & 7)) * 8;
            gload_lds16(A  + (m0 + row) * K + kt + colsw, &lA[c * 512]);
            gload_lds16(Bw + (n0 + row) * K + kt + colsw, &lB[c * 512]);
        }
        __syncthreads();
        #pragma unroll
        for (int ks = 0; ks < 2; ++ks) {
            short8 af[4], bfv[4];
            #pragma unroll
            for (int m = 0; m < 4; ++m) {
                int row = wr * 64 + m * 16 + l15;
                int idx = row * 64 + (((ks * 4 + g) ^ (row & 7)) * 8);
                af[m] = *reinterpret_cast<const short8*>(&lA[idx]);
            }
            #pragma unroll
            for (int n = 0; n < 4; ++n) {
                int row = wc * 64 + n * 16 + l15;
                int idx = row * 64 + (((ks * 4 + g) ^ (row & 7)) * 8);
                bfv[n] = *reinterpret_cast<const short8*>(&lB[idx]);
            }
            #pragma unroll
            for (int m = 0; m < 4; ++m)
                #pragma unroll
                for (int n = 0; n < 4; ++n)
                    acc[m][n] = MFMA16(af[m], bfv[n], acc[m][n]);
        }
    }

    #pragma unroll
    for (int m = 0; m < 4; ++m) {
        #pragma unroll
        for (int n = 0; n < 4; ++n) {
            int col = n0 + wc * 64 + n * 16 + l15;
            #pragma unroll
            for (int r = 0; r < 4; ++r) {
                int row = m0 + wr * 64 + m * 16 + g * 4 + r;
                float v = acc[m][n][r];
                if constexpr (EPI == 0) {
                    int which = (col >= 1536) ? 2 : (col >= 768 ? 1 : 0);
                    int e = col - which * 768;
                    int h = e >> 6, d = e & 63;
                    int b = row >> 11, s = row & 2047;
                    int bh = b * SH + h;
                    bf16* dst = (bf16*)Out;
                    int idx;
                    if (which == 2) idx = 2 * BHSD + (bh * 64 + d) * SS + s;   // V^T [bh][dk][s]
                    else            idx = which * BHSD + (bh * SS + s) * 64 + d;
                    if (which == 0) v *= QSCALE;
                    dst[idx] = __float2bfloat16(v);
                } else {
                    ((float*)Out)[row * SD + col] = v;
                }
            }
        }
    }
}

// ---- flash attention: shared-LDS 4-wave blocks, split-K, exp2-direct ----
// R20: TRIPLE-buffered LDS (48KB) -> ONE barrier per step. Stage at step
// pt+1 targets the buffer computed at pt-1; every wave's reads of it precede
// that wave's barrier at step pt (program order), so the trailing
// write-after-read barrier of the 2-buffer scheme is redundant.
// Everything else R17-verbatim.
__global__ __launch_bounds__(256, 4) void attn_kernel(const bf16* __restrict__ Qb,
                                                      const bf16* __restrict__ Kb,
                                                      const bf16* __restrict__ Vtb,
                                                      float* __restrict__ Op,
                                                      float* __restrict__ lp) {
    __shared__ bf16 lK[3][4096];   // [kv 64][d 64], swizzled
    __shared__ bf16 lV[3][4096];   // [d 64][kv 64], swizzled

    const int bid = blockIdx.x;              // 0..959
    const int xcd = bid & 7, li = bid >> 3;  // li 0..119
    const int g40 = li / 40;                 // 0..2
    const int bh = xcd * 3 + g40;
    const int u = 39 - (li - g40 * 40);      // heavy-first

    int qg, ck;
    if (u < 4)       { qg = u;                           ck = 0; }
    else if (u < 12) { int t = u - 4;  qg = 4 + (t >> 1);  ck = t & 1; }
    else if (u < 24) { int t = u - 12; int q3 = t / 3; qg = 8 + q3; ck = t - 3 * q3; }
    else             { int t = u - 24; qg = 12 + (t >> 2); ck = t & 3; }

    const int tid = threadIdx.x, lane = tid & 63, w = tid >> 6;
    const int l31 = lane & 31, hi = lane >> 5;
    const int srow = lane >> 3, slot = lane & 7;

    const int j  = qg * 4 + w;
    const int jp = 2 * qg + (w >> 1);
    const int p0 = ck * 8;
    const int pe_ = 2 * qg + 1;
    const int pe = (p0 + 7 < pe_) ? (p0 + 7) : pe_;

    const bf16* Qh = Qb + bh * SS * 64;
    const bf16* Kh = Kb + bh * SS * 64;
    const bf16* Vh = Vtb + bh * 64 * SS;

    const int qself = j * 32 + l31;
    short8 qf[4];
    #pragma unroll
    for (int ks = 0; ks < 4; ++ks)
        qf[ks] = *reinterpret_cast<const short8*>(Qh + qself * 64 + ks * 16 + hi * 8);

    f32x16 oacc[2];
    #pragma unroll
    for (int n = 0; n < 2; ++n)
        #pragma unroll
        for (int r = 0; r < 16; ++r) oacc[n][r] = 0.f;
    float lrow = 0.f;

    auto STAGE = [&](int buf, int kt) {
        #pragma unroll
        for (int p = 0; p < 2; ++p) {
            int c = w * 2 + p;
            int row = c * 8 + srow;
            int colsw = (slot ^ (row & 7)) * 8;
            gload_lds16(Kh + (kt * 64 + row) * 64 + colsw, &lK[buf][c * 512]);
            gload_lds16(Vh + row * SS + kt * 64 + colsw, &lV[buf][c * 512]);
        }
    };

    auto HALF = [&](int cur, int T, int h) {
        f32x16 s_;
        #pragma unroll
        for (int r = 0; r < 16; ++r) s_[r] = 0.f;

        __builtin_amdgcn_s_setprio(1);
        #pragma unroll
        for (int ks = 0; ks < 4; ++ks) {
            int row = h * 32 + l31;
            int idx = row * 64 + (((2 * ks + hi) ^ (row & 7)) * 8);
            short8 kf = *reinterpret_cast<const short8*>(&lK[cur][idx]);
            s_ = MFMA32(kf, qf[ks], s_);
        }
        __builtin_amdgcn_s_setprio(0);

        if (T == j) {
            #pragma unroll
            for (int r = 0; r < 16; ++r) {
                int kvrow = (r & 3) + 8 * (r >> 2) + 4 * hi;
                if (kvrow > l31) s_[r] = -1e30f;
            }
        }

        #pragma unroll
        for (int r = 0; r < 16; ++r) s_[r] = exp2f(s_[r]);
        float w0 = ((s_[0] + s_[1]) + (s_[2] + s_[3]))
                 + ((s_[4] + s_[5]) + (s_[6] + s_[7]));
        float w1 = ((s_[8] + s_[9]) + (s_[10] + s_[11]))
                 + ((s_[12] + s_[13]) + (s_[14] + s_[15]));
        lrow += (w0 + w1);

        int a0 = cvtpk(s_[0],  s_[1]),  a1 = cvtpk(s_[2],  s_[3]);
        int b0 = cvtpk(s_[4],  s_[5]),  b1 = cvtpk(s_[6],  s_[7]);
        plswap(a0, b0); plswap(a1, b1);
        int a2 = cvtpk(s_[8],  s_[9]),  a3 = cvtpk(s_[10], s_[11]);
        int b2 = cvtpk(s_[12], s_[13]), b3 = cvtpk(s_[14], s_[15]);
        plswap(a2, b2); plswap(a3, b3);
        union { int wd[4]; short8 s8; } u0_, u1_;
        u0_.wd[0] = a0; u0_.wd[1] = a1; u0_.wd[2] = b0; u0_.wd[3] = b1;
        u1_.wd[0] = a2; u1_.wd[1] = a3; u1_.wd[2] = b2; u1_.wd[3] = b3;

        __builtin_amdgcn_s_setprio(1);
        #pragma unroll
        for (int n = 0; n < 2; ++n) {
            int rowv = n * 32 + l31;
            int base = rowv * 64;
            int sw = rowv & 7;
            short8 vf0 = *reinterpret_cast<const short8*>(&lV[cur][base + (((4 * h + 0 + hi) ^ sw) * 8)]);
            oacc[n] = MFMA32(u0_.s8, vf0, oacc[n]);
            short8 vf1 = *reinterpret_cast<const short8*>(&lV[cur][base + (((4 * h + 2 + hi) ^ sw) * 8)]);
            oacc[n] = MFMA32(u1_.s8, vf1, oacc[n]);
        }
        __builtin_amdgcn_s_setprio(0);
    };

    STAGE(0, p0);

    for (int pt = p0; pt <= pe; ++pt) {
        const int cur = (pt - p0) % 3;
        if (pt < pe) {
            STAGE((pt - p0 + 1) % 3, pt + 1);
            asm volatile("s_waitcnt vmcnt(4)" ::: "memory");   // tile-pt loads landed
        } else {
            asm volatile("s_waitcnt vmcnt(0)" ::: "memory");
        }
        __builtin_amdgcn_sched_barrier(0);
        __builtin_amdgcn_s_barrier();          // single barrier per step
        __builtin_amdgcn_sched_barrier(0);

        if (pt <= jp) {
            const int T0 = 2 * pt, T1 = T0 + 1;
            HALF(cur, T0, 0);
            if (T1 <= j) HALF(cur, T1, 1);
        }
    }

    const int qrow0 = bh * SS + j * 32;
    atomicAdd(&lp[qrow0 + l31], lrow);
    #pragma unroll
    for (int n = 0; n < 2; ++n) {
        #pragma unroll
        for (int r = 0; r < 16; ++r) {
            int q = (r & 3) + 8 * (r >> 2) + 4 * hi;
            int d = n * 32 + l31;
            atomicAdd(&Op[(qrow0 + q) * 64 + d], oacc[n][r]);
        }
    }
}

// ---- normalize (x4 vectorized): AO[b,s,h*64+d] = Op[bh,s,d] / lp[bh,s] ----
__global__ __launch_bounds__(256) void norm_kernel(const float4* __restrict__ Op,
                                                   const float* __restrict__ lp,
                                                   uint64_t* __restrict__ AO) {
    int i4 = blockIdx.x * 256 + threadIdx.x;      // 0 .. 786431 (4 elems each)
    int idx = i4 << 2;
    int d = idx & 63, srow = idx >> 6;            // srow = bh*2048 + s
    int bh = srow >> 11, s = srow & 2047;
    int b = bh / SH, h = bh - b * SH;
    float inv = 1.0f / lp[srow];
    float4 v = Op[i4];
    union { bf16 hh[4]; uint64_t u; } p;
    p.hh[0] = __float2bfloat16(v.x * inv);
    p.hh[1] = __float2bfloat16(v.y * inv);
    p.hh[2] = __float2bfloat16(v.z * inv);
    p.hh[3] = __float2bfloat16(v.w * inv);
    AO[(((b * SS + s) * SD + h * 64 + d) >> 2)] = p.u;
}

extern "C" void kernel_launch(void* const* d_in, const int* in_sizes, int n_in,
                              void* d_out, int out_size, void* d_ws, size_t ws_size,
                              hipStream_t stream) {
    const float* x  = (const float*)d_in[0];
    const float* wq = (const float*)d_in[1];
    const float* wk = (const float*)d_in[2];
    const float* wv = (const float*)d_in[3];
    const float* wo = (const float*)d_in[4];
    float* out = (float*)d_out;

    bf16* xb   = (bf16*)d_ws;              // reused as ao after gemm<0>
    bf16* wqkv = xb + SM * SD;
    bf16* wob  = wqkv + 3 * SD * SD;
    bf16* qkv  = wob + SD * SD;            // Q, K, V^T
    float* Op  = (float*)(qkv + 3 * BHSD); // 3,145,728 f32 partial O'
    float* lp  = Op + 3145728;             // 49,152 f32
    bf16* ao   = xb;

    // zero split-K accumulators: (3145728 + 49152)/4 = 798720 float4
    zero_ws<<<3120, 256, 0, stream>>>((float4*)Op);

    cvt_all<<<3072 + 4 * 576, 256, 0, stream>>>(
        (const float4*)x, (const float4*)wq, (const float4*)wk,
        (const float4*)wv, (const float4*)wo,
        (uint64_t*)xb, (uint64_t*)wqkv, (uint64_t*)wob);

    gemm_bt<0><<<dim3(2304 / 128, SM / 128), 256, 0, stream>>>(xb, wqkv, (void*)qkv, SD);
    attn_kernel<<<960, 256, 0, stream>>>(qkv, qkv + BHSD, qkv + 2 * BHSD, Op, lp);
    norm_kernel<<<3072, 256, 0, stream>>>((const float4*)Op, lp, (uint64_t*)ao);
    gemm_bt<1><<<dim3(SD / 128, SM / 128), 256, 0, stream>>>(ao, wob, (void*)out, SD);
}

// Round 21
// 115.925 us; speedup vs baseline: 1.0414x; 1.0414x over previous
//
#include <hip/hip_runtime.h>
#include <hip/hip_bf16.h>
#include <stdint.h>

typedef __hip_bfloat16 bf16;
typedef __attribute__((ext_vector_type(8))) short short8;
typedef __attribute__((ext_vector_type(4))) float f32x4;
typedef __attribute__((ext_vector_type(16))) float f32x16;

#define MFMA16(A, B, C) __builtin_amdgcn_mfma_f32_16x16x32_bf16(A, B, C, 0, 0, 0)
#define MFMA32(A, B, C) __builtin_amdgcn_mfma_f32_32x32x16_bf16(A, B, C, 0, 0, 0)

// ---- constants ----
#define SB 2
#define SS 2048
#define SD 768
#define SH 12
#define SM (SB*SS)            // 4096 rows
#define BHSD (SB*SH*SS*64)    // 3145728 elems per Q/K/V
// (1/sqrt(64)) * log2(e) folded into Q at projection time -> attn works in exp2 domain
#define QSCALE 0.18033688011112042f

__device__ __forceinline__ void gload_lds16(const bf16* g, bf16* l) {
    __builtin_amdgcn_global_load_lds(
        (const __attribute__((address_space(1))) void*)(g),
        (__attribute__((address_space(3))) void*)(l),
        16, 0, 0);
}

// f32 pair -> packed bf16 (lo=a, hi=b)
__device__ __forceinline__ int cvtpk(float a, float b) {
    int r;
    asm("v_cvt_pk_bf16_f32 %0, %1, %2" : "=v"(r) : "v"(a), "v"(b));
    return r;
}
// a's lanes 32-63 <-> b's lanes 0-31
__device__ __forceinline__ void plswap(int& a, int& b) {
    asm("v_permlane32_swap_b32 %0, %1" : "+v"(a), "+v"(b));
}

// ---- workspace zero ----
__global__ void zero_ws(float4* __restrict__ p) {
    p[blockIdx.x * 256 + threadIdx.x] = make_float4(0.f, 0.f, 0.f, 0.f);
}

// ---- fused f32 -> bf16 convert for x + 4 weights ----
__global__ void cvt_all(const float4* __restrict__ x,  const float4* __restrict__ w0,
                        const float4* __restrict__ w1, const float4* __restrict__ w2,
                        const float4* __restrict__ w3,
                        uint64_t* __restrict__ xb, uint64_t* __restrict__ wqkv,
                        uint64_t* __restrict__ wob) {
    int bid = blockIdx.x;
    const float4* s; uint64_t* d; int base;
    if (bid < 3072) { s = x; d = xb; base = bid << 8; }
    else {
        int t = bid - 3072, seg = t / 576, li = t - seg * 576;
        s = (seg == 0) ? w0 : (seg == 1) ? w1 : (seg == 2) ? w2 : w3;
        d = (seg < 3) ? (wqkv + seg * 147456) : wob;
        base = li << 8;
    }
    int i = base + threadIdx.x;
    float4 v = s[i];
    union { bf16 h[4]; uint64_t u; } p;
    p.h[0] = __float2bfloat16(v.x);
    p.h[1] = __float2bfloat16(v.y);
    p.h[2] = __float2bfloat16(v.z);
    p.h[3] = __float2bfloat16(v.w);
    d[i] = p.u;
}

// ---- MFMA GEMM: Y = A[M,K] @ Bw[N,K]^T, 128x128 tile, BK=64 ----
template<int EPI>
__global__ __launch_bounds__(256) void gemm_bt(const bf16* __restrict__ A,
                                               const bf16* __restrict__ Bw,
                                               void* __restrict__ Out,
                                               int K) {
    __shared__ bf16 lA[128 * 64];
    __shared__ bf16 lB[128 * 64];
    const int tid  = threadIdx.x;
    const int lane = tid & 63;
    const int wid  = tid >> 6;
    const int wr = wid >> 1, wc = wid & 1;
    const int m0 = blockIdx.y * 128, n0 = blockIdx.x * 128;
    const int g = lane >> 4, l15 = lane & 15;
    const int srow = lane >> 3, slot = lane & 7;

    f32x4 acc[4][4] = {};

    for (int kt = 0; kt < K; kt += 64) {
        __syncthreads();
        #pragma unroll
        for (int p = 0; p < 4; ++p) {
            int c = wid * 4 + p;
            int row = c * 8 + srow;
            int colsw = (slot ^ (row & 7)) * 8;
            gload_lds16(A  + (m0 + row) * K + kt + colsw, &lA[c * 512]);
            gload_lds16(Bw + (n0 + row) * K + kt + colsw, &lB[c * 512]);
        }
        __syncthreads();
        #pragma unroll
        for (int ks = 0; ks < 2; ++ks) {
            short8 af[4], bfv[4];
            #pragma unroll
            for (int m = 0; m < 4; ++m) {
                int row = wr * 64 + m * 16 + l15;
                int idx = row * 64 + (((ks * 4 + g) ^ (row & 7)) * 8);
                af[m] = *reinterpret_cast<const short8*>(&lA[idx]);
            }
            #pragma unroll
            for (int n = 0; n < 4; ++n) {
                int row = wc * 64 + n * 16 + l15;
                int idx = row * 64 + (((ks * 4 + g) ^ (row & 7)) * 8);
                bfv[n] = *reinterpret_cast<const short8*>(&lB[idx]);
            }
            #pragma unroll
            for (int m = 0; m < 4; ++m)
                #pragma unroll
                for (int n = 0; n < 4; ++n)
                    acc[m][n] = MFMA16(af[m], bfv[n], acc[m][n]);
        }
    }

    #pragma unroll
    for (int m = 0; m < 4; ++m) {
        #pragma unroll
        for (int n = 0; n < 4; ++n) {
            int col = n0 + wc * 64 + n * 16 + l15;
            #pragma unroll
            for (int r = 0; r < 4; ++r) {
                int row = m0 + wr * 64 + m * 16 + g * 4 + r;
                float v = acc[m][n][r];
                if constexpr (EPI == 0) {
                    int which = (col >= 1536) ? 2 : (col >= 768 ? 1 : 0);
                    int e = col - which * 768;
                    int h = e >> 6, d = e & 63;
                    int b = row >> 11, s = row & 2047;
                    int bh = b * SH + h;
                    bf16* dst = (bf16*)Out;
                    int idx;
                    if (which == 2) idx = 2 * BHSD + (bh * 64 + d) * SS + s;   // V^T [bh][dk][s]
                    else            idx = which * BHSD + (bh * SS + s) * 64 + d;
                    if (which == 0) v *= QSCALE;
                    dst[idx] = __float2bfloat16(v);
                } else {
                    ((float*)Out)[row * SD + col] = v;
                }
            }
        }
    }
}

// ---- flash attention: R17-EXACT (2-buffer, 2-barrier, VGPR 56) ----
// R20's triple-buffer regressed (VGPR 56->80, occupancy 22.7->17.7%):
// registers dominate barrier count in this kernel. Reverted.
__global__ __launch_bounds__(256, 4) void attn_kernel(const bf16* __restrict__ Qb,
                                                      const bf16* __restrict__ Kb,
                                                      const bf16* __restrict__ Vtb,
                                                      float* __restrict__ Op,
                                                      float* __restrict__ lp) {
    __shared__ bf16 lK[2][4096];   // [kv 64][d 64], swizzled
    __shared__ bf16 lV[2][4096];   // [d 64][kv 64], swizzled

    const int bid = blockIdx.x;              // 0..959
    const int xcd = bid & 7, li = bid >> 3;  // li 0..119
    const int g40 = li / 40;                 // 0..2
    const int bh = xcd * 3 + g40;
    const int u = 39 - (li - g40 * 40);      // heavy-first

    int qg, ck;
    if (u < 4)       { qg = u;                           ck = 0; }
    else if (u < 12) { int t = u - 4;  qg = 4 + (t >> 1);  ck = t & 1; }
    else if (u < 24) { int t = u - 12; int q3 = t / 3; qg = 8 + q3; ck = t - 3 * q3; }
    else             { int t = u - 24; qg = 12 + (t >> 2); ck = t & 3; }

    const int tid = threadIdx.x, lane = tid & 63, w = tid >> 6;
    const int l31 = lane & 31, hi = lane >> 5;
    const int srow = lane >> 3, slot = lane & 7;

    const int j  = qg * 4 + w;
    const int jp = 2 * qg + (w >> 1);
    const int p0 = ck * 8;
    const int pe_ = 2 * qg + 1;
    const int pe = (p0 + 7 < pe_) ? (p0 + 7) : pe_;

    const bf16* Qh = Qb + bh * SS * 64;
    const bf16* Kh = Kb + bh * SS * 64;
    const bf16* Vh = Vtb + bh * 64 * SS;

    const int qself = j * 32 + l31;
    short8 qf[4];
    #pragma unroll
    for (int ks = 0; ks < 4; ++ks)
        qf[ks] = *reinterpret_cast<const short8*>(Qh + qself * 64 + ks * 16 + hi * 8);

    f32x16 oacc[2];
    #pragma unroll
    for (int n = 0; n < 2; ++n)
        #pragma unroll
        for (int r = 0; r < 16; ++r) oacc[n][r] = 0.f;
    float lrow = 0.f;

    auto STAGE = [&](int buf, int kt) {
        #pragma unroll
        for (int p = 0; p < 2; ++p) {
            int c = w * 2 + p;
            int row = c * 8 + srow;
            int colsw = (slot ^ (row & 7)) * 8;
            gload_lds16(Kh + (kt * 64 + row) * 64 + colsw, &lK[buf][c * 512]);
            gload_lds16(Vh + row * SS + kt * 64 + colsw, &lV[buf][c * 512]);
        }
    };

    auto HALF = [&](int cur, int T, int h) {
        f32x16 s_;
        #pragma unroll
        for (int r = 0; r < 16; ++r) s_[r] = 0.f;

        __builtin_amdgcn_s_setprio(1);
        #pragma unroll
        for (int ks = 0; ks < 4; ++ks) {
            int row = h * 32 + l31;
            int idx = row * 64 + (((2 * ks + hi) ^ (row & 7)) * 8);
            short8 kf = *reinterpret_cast<const short8*>(&lK[cur][idx]);
            s_ = MFMA32(kf, qf[ks], s_);
        }
        __builtin_amdgcn_s_setprio(0);

        if (T == j) {
            #pragma unroll
            for (int r = 0; r < 16; ++r) {
                int kvrow = (r & 3) + 8 * (r >> 2) + 4 * hi;
                if (kvrow > l31) s_[r] = -1e30f;
            }
        }

        #pragma unroll
        for (int r = 0; r < 16; ++r) s_[r] = exp2f(s_[r]);
        float w0 = ((s_[0] + s_[1]) + (s_[2] + s_[3]))
                 + ((s_[4] + s_[5]) + (s_[6] + s_[7]));
        float w1 = ((s_[8] + s_[9]) + (s_[10] + s_[11]))
                 + ((s_[12] + s_[13]) + (s_[14] + s_[15]));
        lrow += (w0 + w1);

        int a0 = cvtpk(s_[0],  s_[1]),  a1 = cvtpk(s_[2],  s_[3]);
        int b0 = cvtpk(s_[4],  s_[5]),  b1 = cvtpk(s_[6],  s_[7]);
        plswap(a0, b0); plswap(a1, b1);
        int a2 = cvtpk(s_[8],  s_[9]),  a3 = cvtpk(s_[10], s_[11]);
        int b2 = cvtpk(s_[12], s_[13]), b3 = cvtpk(s_[14], s_[15]);
        plswap(a2, b2); plswap(a3, b3);
        union { int wd[4]; short8 s8; } u0_, u1_;
        u0_.wd[0] = a0; u0_.wd[1] = a1; u0_.wd[2] = b0; u0_.wd[3] = b1;
        u1_.wd[0] = a2; u1_.wd[1] = a3; u1_.wd[2] = b2; u1_.wd[3] = b3;

        __builtin_amdgcn_s_setprio(1);
        #pragma unroll
        for (int n = 0; n < 2; ++n) {
            int rowv = n * 32 + l31;
            int base = rowv * 64;
            int sw = rowv & 7;
            short8 vf0 = *reinterpret_cast<const short8*>(&lV[cur][base + (((4 * h + 0 + hi) ^ sw) * 8)]);
            oacc[n] = MFMA32(u0_.s8, vf0, oacc[n]);
            short8 vf1 = *reinterpret_cast<const short8*>(&lV[cur][base + (((4 * h + 2 + hi) ^ sw) * 8)]);
            oacc[n] = MFMA32(u1_.s8, vf1, oacc[n]);
        }
        __builtin_amdgcn_s_setprio(0);
    };

    STAGE(0, p0);

    int cur = 0;
    for (int pt = p0; pt <= pe; ++pt) {
        if (pt < pe) {
            STAGE(cur ^ 1, pt + 1);
            asm volatile("s_waitcnt vmcnt(4)" ::: "memory");
        } else {
            asm volatile("s_waitcnt vmcnt(0)" ::: "memory");
        }
        __builtin_amdgcn_sched_barrier(0);
        __builtin_amdgcn_s_barrier();
        __builtin_amdgcn_sched_barrier(0);

        if (pt <= jp) {
            const int T0 = 2 * pt, T1 = T0 + 1;
            HALF(cur, T0, 0);
            if (T1 <= j) HALF(cur, T1, 1);
        }

        __builtin_amdgcn_s_barrier();
        cur ^= 1;
    }

    const int qrow0 = bh * SS + j * 32;
    atomicAdd(&lp[qrow0 + l31], lrow);
    #pragma unroll
    for (int n = 0; n < 2; ++n) {
        #pragma unroll
        for (int r = 0; r < 16; ++r) {
            int q = (r & 3) + 8 * (r >> 2) + 4 * hi;
            int d = n * 32 + l31;
            atomicAdd(&Op[(qrow0 + q) * 64 + d], oacc[n][r]);
        }
    }
}

// ---- normalize (x4 vectorized): AO[b,s,h*64+d] = Op[bh,s,d] / lp[bh,s] ----
__global__ __launch_bounds__(256) void norm_kernel(const float4* __restrict__ Op,
                                                   const float* __restrict__ lp,
                                                   uint64_t* __restrict__ AO) {
    int i4 = blockIdx.x * 256 + threadIdx.x;      // 0 .. 786431 (4 elems each)
    int idx = i4 << 2;
    int d = idx & 63, srow = idx >> 6;            // srow = bh*2048 + s
    int bh = srow >> 11, s = srow & 2047;
    int b = bh / SH, h = bh - b * SH;
    float inv = 1.0f / lp[srow];
    float4 v = Op[i4];
    union { bf16 hh[4]; uint64_t u; } p;
    p.hh[0] = __float2bfloat16(v.x * inv);
    p.hh[1] = __float2bfloat16(v.y * inv);
    p.hh[2] = __float2bfloat16(v.z * inv);
    p.hh[3] = __float2bfloat16(v.w * inv);
    AO[(((b * SS + s) * SD + h * 64 + d) >> 2)] = p.u;
}

extern "C" void kernel_launch(void* const* d_in, const int* in_sizes, int n_in,
                              void* d_out, int out_size, void* d_ws, size_t ws_size,
                              hipStream_t stream) {
    const float* x  = (const float*)d_in[0];
    const float* wq = (const float*)d_in[1];
    const float* wk = (const float*)d_in[2];
    const float* wv = (const float*)d_in[3];
    const float* wo = (const float*)d_in[4];
    float* out = (float*)d_out;

    bf16* xb   = (bf16*)d_ws;              // reused as ao after gemm<0>
    bf16* wqkv = xb + SM * SD;
    bf16* wob  = wqkv + 3 * SD * SD;
    bf16* qkv  = wob + SD * SD;            // Q, K, V^T
    float* Op  = (float*)(qkv + 3 * BHSD); // 3,145,728 f32 partial O'
    float* lp  = Op + 3145728;             // 49,152 f32
    bf16* ao   = xb;

    // zero split-K accumulators: (3145728 + 49152)/4 = 798720 float4
    zero_ws<<<3120, 256, 0, stream>>>((float4*)Op);

    cvt_all<<<3072 + 4 * 576, 256, 0, stream>>>(
        (const float4*)x, (const float4*)wq, (const float4*)wk,
        (const float4*)wv, (const float4*)wo,
        (uint64_t*)xb, (uint64_t*)wqkv, (uint64_t*)wob);

    gemm_bt<0><<<dim3(2304 / 128, SM / 128), 256, 0, stream>>>(xb, wqkv, (void*)qkv, SD);
    attn_kernel<<<960, 256, 0, stream>>>(qkv, qkv + BHSD, qkv + 2 * BHSD, Op, lp);
    norm_kernel<<<3072, 256, 0, stream>>>((const float4*)Op, lp, (uint64_t*)ao);
    gemm_bt<1><<<dim3(SD / 128, SM / 128), 256, 0, stream>>>(ao, wob, (void*)out, SD);
}

// Round 22
// 106.985 us; speedup vs baseline: 1.1284x; 1.0836x over previous
//
#include <hip/hip_runtime.h>
#include <hip/hip_bf16.h>
#include <stdint.h>

typedef __hip_bfloat16 bf16;
typedef __attribute__((ext_vector_type(8))) short short8;
typedef __attribute__((ext_vector_type(4))) float f32x4;
typedef __attribute__((ext_vector_type(16))) float f32x16;

#define MFMA16(A, B, C) __builtin_amdgcn_mfma_f32_16x16x32_bf16(A, B, C, 0, 0, 0)
#define MFMA32(A, B, C) __builtin_amdgcn_mfma_f32_32x32x16_bf16(A, B, C, 0, 0, 0)

// ---- constants ----
#define SB 2
#define SS 2048
#define SD 768
#define SH 12
#define SM (SB*SS)            // 4096 rows
#define BHSD (SB*SH*SS*64)    // 3145728 elems per Q/K/V
// (1/sqrt(64)) * log2(e) folded into Q at projection time -> attn works in exp2 domain
#define QSCALE 0.18033688011112042f

__device__ __forceinline__ void gload_lds16(const bf16* g, bf16* l) {
    __builtin_amdgcn_global_load_lds(
        (const __attribute__((address_space(1))) void*)(g),
        (__attribute__((address_space(3))) void*)(l),
        16, 0, 0);
}

// f32 pair -> packed bf16 (lo=a, hi=b)
__device__ __forceinline__ int cvtpk(float a, float b) {
    int r;
    asm("v_cvt_pk_bf16_f32 %0, %1, %2" : "=v"(r) : "v"(a), "v"(b));
    return r;
}
// a's lanes 32-63 <-> b's lanes 0-31
__device__ __forceinline__ void plswap(int& a, int& b) {
    asm("v_permlane32_swap_b32 %0, %1" : "+v"(a), "+v"(b));
}

// ---- workspace zero ----
__global__ void zero_ws(float4* __restrict__ p) {
    p[blockIdx.x * 256 + threadIdx.x] = make_float4(0.f, 0.f, 0.f, 0.f);
}

// ---- fused f32 -> bf16 convert for x + 4 weights ----
__global__ void cvt_all(const float4* __restrict__ x,  const float4* __restrict__ w0,
                        const float4* __restrict__ w1, const float4* __restrict__ w2,
                        const float4* __restrict__ w3,
                        uint64_t* __restrict__ xb, uint64_t* __restrict__ wqkv,
                        uint64_t* __restrict__ wob) {
    int bid = blockIdx.x;
    const float4* s; uint64_t* d; int base;
    if (bid < 3072) { s = x; d = xb; base = bid << 8; }
    else {
        int t = bid - 3072, seg = t / 576, li = t - seg * 576;
        s = (seg == 0) ? w0 : (seg == 1) ? w1 : (seg == 2) ? w2 : w3;
        d = (seg < 3) ? (wqkv + seg * 147456) : wob;
        base = li << 8;
    }
    int i = base + threadIdx.x;
    float4 v = s[i];
    union { bf16 h[4]; uint64_t u; } p;
    p.h[0] = __float2bfloat16(v.x);
    p.h[1] = __float2bfloat16(v.y);
    p.h[2] = __float2bfloat16(v.z);
    p.h[3] = __float2bfloat16(v.w);
    d[i] = p.u;
}

// ---- MFMA GEMM: Y = A[M,K] @ Bw[N,K]^T, BM=64 x BN=128 tile, BK=64 ----
// R22: tile 128x128 -> 64x128 for 2x grid (gemm<0>: 576->1152 blocks 4.5/CU,
// gemm<1>: 192->384 blocks 1.5/CU — both were grid-starved). Waves 2x2, each
// 32x64 output (acc[2][4], 32 VGPR). Staging/swizzle math unchanged:
// A = 8 chunks (2/wave), B = 16 chunks (4/wave).
template<int EPI>
__global__ __launch_bounds__(256) void gemm_bt(const bf16* __restrict__ A,
                                               const bf16* __restrict__ Bw,
                                               void* __restrict__ Out,
                                               int K) {
    __shared__ bf16 lA[64 * 64];
    __shared__ bf16 lB[128 * 64];
    const int tid  = threadIdx.x;
    const int lane = tid & 63;
    const int wid  = tid >> 6;
    const int wr = wid >> 1, wc = wid & 1;
    const int m0 = blockIdx.y * 64, n0 = blockIdx.x * 128;
    const int g = lane >> 4, l15 = lane & 15;
    const int srow = lane >> 3, slot = lane & 7;

    f32x4 acc[2][4] = {};

    for (int kt = 0; kt < K; kt += 64) {
        __syncthreads();
        #pragma unroll
        for (int p = 0; p < 2; ++p) {
            int c = wid * 2 + p;                 // A chunks 0..7 (8 rows each)
            int row = c * 8 + srow;
            int colsw = (slot ^ (row & 7)) * 8;
            gload_lds16(A + (m0 + row) * K + kt + colsw, &lA[c * 512]);
        }
        #pragma unroll
        for (int p = 0; p < 4; ++p) {
            int c = wid * 4 + p;                 // B chunks 0..15
            int row = c * 8 + srow;
            int colsw = (slot ^ (row & 7)) * 8;
            gload_lds16(Bw + (n0 + row) * K + kt + colsw, &lB[c * 512]);
        }
        __syncthreads();
        #pragma unroll
        for (int ks = 0; ks < 2; ++ks) {
            short8 af[2], bfv[4];
            #pragma unroll
            for (int m = 0; m < 2; ++m) {
                int row = wr * 32 + m * 16 + l15;
                int idx = row * 64 + (((ks * 4 + g) ^ (row & 7)) * 8);
                af[m] = *reinterpret_cast<const short8*>(&lA[idx]);
            }
            #pragma unroll
            for (int n = 0; n < 4; ++n) {
                int row = wc * 64 + n * 16 + l15;
                int idx = row * 64 + (((ks * 4 + g) ^ (row & 7)) * 8);
                bfv[n] = *reinterpret_cast<const short8*>(&lB[idx]);
            }
            #pragma unroll
            for (int m = 0; m < 2; ++m)
                #pragma unroll
                for (int n = 0; n < 4; ++n)
                    acc[m][n] = MFMA16(af[m], bfv[n], acc[m][n]);
        }
    }

    #pragma unroll
    for (int m = 0; m < 2; ++m) {
        #pragma unroll
        for (int n = 0; n < 4; ++n) {
            int col = n0 + wc * 64 + n * 16 + l15;
            #pragma unroll
            for (int r = 0; r < 4; ++r) {
                int row = m0 + wr * 32 + m * 16 + g * 4 + r;
                float v = acc[m][n][r];
                if constexpr (EPI == 0) {
                    int which = (col >= 1536) ? 2 : (col >= 768 ? 1 : 0);
                    int e = col - which * 768;
                    int h = e >> 6, d = e & 63;
                    int b = row >> 11, s = row & 2047;
                    int bh = b * SH + h;
                    bf16* dst = (bf16*)Out;
                    int idx;
                    if (which == 2) idx = 2 * BHSD + (bh * 64 + d) * SS + s;   // V^T [bh][dk][s]
                    else            idx = which * BHSD + (bh * SS + s) * 64 + d;
                    if (which == 0) v *= QSCALE;
                    dst[idx] = __float2bfloat16(v);
                } else {
                    ((float*)Out)[row * SD + col] = v;
                }
            }
        }
    }
}

// ---- flash attention: R17-EXACT (2-buffer, 2-barrier, VGPR 56) ----
__global__ __launch_bounds__(256, 4) void attn_kernel(const bf16* __restrict__ Qb,
                                                      const bf16* __restrict__ Kb,
                                                      const bf16* __restrict__ Vtb,
                                                      float* __restrict__ Op,
                                                      float* __restrict__ lp) {
    __shared__ bf16 lK[2][4096];   // [kv 64][d 64], swizzled
    __shared__ bf16 lV[2][4096];   // [d 64][kv 64], swizzled

    const int bid = blockIdx.x;              // 0..959
    const int xcd = bid & 7, li = bid >> 3;  // li 0..119
    const int g40 = li / 40;                 // 0..2
    const int bh = xcd * 3 + g40;
    const int u = 39 - (li - g40 * 40);      // heavy-first

    int qg, ck;
    if (u < 4)       { qg = u;                           ck = 0; }
    else if (u < 12) { int t = u - 4;  qg = 4 + (t >> 1);  ck = t & 1; }
    else if (u < 24) { int t = u - 12; int q3 = t / 3; qg = 8 + q3; ck = t - 3 * q3; }
    else             { int t = u - 24; qg = 12 + (t >> 2); ck = t & 3; }

    const int tid = threadIdx.x, lane = tid & 63, w = tid >> 6;
    const int l31 = lane & 31, hi = lane >> 5;
    const int srow = lane >> 3, slot = lane & 7;

    const int j  = qg * 4 + w;
    const int jp = 2 * qg + (w >> 1);
    const int p0 = ck * 8;
    const int pe_ = 2 * qg + 1;
    const int pe = (p0 + 7 < pe_) ? (p0 + 7) : pe_;

    const bf16* Qh = Qb + bh * SS * 64;
    const bf16* Kh = Kb + bh * SS * 64;
    const bf16* Vh = Vtb + bh * 64 * SS;

    const int qself = j * 32 + l31;
    short8 qf[4];
    #pragma unroll
    for (int ks = 0; ks < 4; ++ks)
        qf[ks] = *reinterpret_cast<const short8*>(Qh + qself * 64 + ks * 16 + hi * 8);

    f32x16 oacc[2];
    #pragma unroll
    for (int n = 0; n < 2; ++n)
        #pragma unroll
        for (int r = 0; r < 16; ++r) oacc[n][r] = 0.f;
    float lrow = 0.f;

    auto STAGE = [&](int buf, int kt) {
        #pragma unroll
        for (int p = 0; p < 2; ++p) {
            int c = w * 2 + p;
            int row = c * 8 + srow;
            int colsw = (slot ^ (row & 7)) * 8;
            gload_lds16(Kh + (kt * 64 + row) * 64 + colsw, &lK[buf][c * 512]);
            gload_lds16(Vh + row * SS + kt * 64 + colsw, &lV[buf][c * 512]);
        }
    };

    auto HALF = [&](int cur, int T, int h) {
        f32x16 s_;
        #pragma unroll
        for (int r = 0; r < 16; ++r) s_[r] = 0.f;

        __builtin_amdgcn_s_setprio(1);
        #pragma unroll
        for (int ks = 0; ks < 4; ++ks) {
            int row = h * 32 + l31;
            int idx = row * 64 + (((2 * ks + hi) ^ (row & 7)) * 8);
            short8 kf = *reinterpret_cast<const short8*>(&lK[cur][idx]);
            s_ = MFMA32(kf, qf[ks], s_);
        }
        __builtin_amdgcn_s_setprio(0);

        if (T == j) {
            #pragma unroll
            for (int r = 0; r < 16; ++r) {
                int kvrow = (r & 3) + 8 * (r >> 2) + 4 * hi;
                if (kvrow > l31) s_[r] = -1e30f;
            }
        }

        #pragma unroll
        for (int r = 0; r < 16; ++r) s_[r] = exp2f(s_[r]);
        float w0 = ((s_[0] + s_[1]) + (s_[2] + s_[3]))
                 + ((s_[4] + s_[5]) + (s_[6] + s_[7]));
        float w1 = ((s_[8] + s_[9]) + (s_[10] + s_[11]))
                 + ((s_[12] + s_[13]) + (s_[14] + s_[15]));
        lrow += (w0 + w1);

        int a0 = cvtpk(s_[0],  s_[1]),  a1 = cvtpk(s_[2],  s_[3]);
        int b0 = cvtpk(s_[4],  s_[5]),  b1 = cvtpk(s_[6],  s_[7]);
        plswap(a0, b0); plswap(a1, b1);
        int a2 = cvtpk(s_[8],  s_[9]),  a3 = cvtpk(s_[10], s_[11]);
        int b2 = cvtpk(s_[12], s_[13]), b3 = cvtpk(s_[14], s_[15]);
        plswap(a2, b2); plswap(a3, b3);
        union { int wd[4]; short8 s8; } u0_, u1_;
        u0_.wd[0] = a0; u0_.wd[1] = a1; u0_.wd[2] = b0; u0_.wd[3] = b1;
        u1_.wd[0] = a2; u1_.wd[1] = a3; u1_.wd[2] = b2; u1_.wd[3] = b3;

        __builtin_amdgcn_s_setprio(1);
        #pragma unroll
        for (int n = 0; n < 2; ++n) {
            int rowv = n * 32 + l31;
            int base = rowv * 64;
            int sw = rowv & 7;
            short8 vf0 = *reinterpret_cast<const short8*>(&lV[cur][base + (((4 * h + 0 + hi) ^ sw) * 8)]);
            oacc[n] = MFMA32(u0_.s8, vf0, oacc[n]);
            short8 vf1 = *reinterpret_cast<const short8*>(&lV[cur][base + (((4 * h + 2 + hi) ^ sw) * 8)]);
            oacc[n] = MFMA32(u1_.s8, vf1, oacc[n]);
        }
        __builtin_amdgcn_s_setprio(0);
    };

    STAGE(0, p0);

    int cur = 0;
    for (int pt = p0; pt <= pe; ++pt) {
        if (pt < pe) {
            STAGE(cur ^ 1, pt + 1);
            asm volatile("s_waitcnt vmcnt(4)" ::: "memory");
        } else {
            asm volatile("s_waitcnt vmcnt(0)" ::: "memory");
        }
        __builtin_amdgcn_sched_barrier(0);
        __builtin_amdgcn_s_barrier();
        __builtin_amdgcn_sched_barrier(0);

        if (pt <= jp) {
            const int T0 = 2 * pt, T1 = T0 + 1;
            HALF(cur, T0, 0);
            if (T1 <= j) HALF(cur, T1, 1);
        }

        __builtin_amdgcn_s_barrier();
        cur ^= 1;
    }

    const int qrow0 = bh * SS + j * 32;
    atomicAdd(&lp[qrow0 + l31], lrow);
    #pragma unroll
    for (int n = 0; n < 2; ++n) {
        #pragma unroll
        for (int r = 0; r < 16; ++r) {
            int q = (r & 3) + 8 * (r >> 2) + 4 * hi;
            int d = n * 32 + l31;
            atomicAdd(&Op[(qrow0 + q) * 64 + d], oacc[n][r]);
        }
    }
}

// ---- normalize (x4 vectorized): AO[b,s,h*64+d] = Op[bh,s,d] / lp[bh,s] ----
__global__ __launch_bounds__(256) void norm_kernel(const float4* __restrict__ Op,
                                                   const float* __restrict__ lp,
                                                   uint64_t* __restrict__ AO) {
    int i4 = blockIdx.x * 256 + threadIdx.x;      // 0 .. 786431 (4 elems each)
    int idx = i4 << 2;
    int d = idx & 63, srow = idx >> 6;            // srow = bh*2048 + s
    int bh = srow >> 11, s = srow & 2047;
    int b = bh / SH, h = bh - b * SH;
    float inv = 1.0f / lp[srow];
    float4 v = Op[i4];
    union { bf16 hh[4]; uint64_t u; } p;
    p.hh[0] = __float2bfloat16(v.x * inv);
    p.hh[1] = __float2bfloat16(v.y * inv);
    p.hh[2] = __float2bfloat16(v.z * inv);
    p.hh[3] = __float2bfloat16(v.w * inv);
    AO[(((b * SS + s) * SD + h * 64 + d) >> 2)] = p.u;
}

extern "C" void kernel_launch(void* const* d_in, const int* in_sizes, int n_in,
                              void* d_out, int out_size, void* d_ws, size_t ws_size,
                              hipStream_t stream) {
    const float* x  = (const float*)d_in[0];
    const float* wq = (const float*)d_in[1];
    const float* wk = (const float*)d_in[2];
    const float* wv = (const float*)d_in[3];
    const float* wo = (const float*)d_in[4];
    float* out = (float*)d_out;

    bf16* xb   = (bf16*)d_ws;              // reused as ao after gemm<0>
    bf16* wqkv = xb + SM * SD;
    bf16* wob  = wqkv + 3 * SD * SD;
    bf16* qkv  = wob + SD * SD;            // Q, K, V^T
    float* Op  = (float*)(qkv + 3 * BHSD); // 3,145,728 f32 partial O'
    float* lp  = Op + 3145728;             // 49,152 f32
    bf16* ao   = xb;

    // zero split-K accumulators: (3145728 + 49152)/4 = 798720 float4
    zero_ws<<<3120, 256, 0, stream>>>((float4*)Op);

    cvt_all<<<3072 + 4 * 576, 256, 0, stream>>>(
        (const float4*)x, (const float4*)wq, (const float4*)wk,
        (const float4*)wv, (const float4*)wo,
        (uint64_t*)xb, (uint64_t*)wqkv, (uint64_t*)wob);

    gemm_bt<0><<<dim3(2304 / 128, SM / 64), 256, 0, stream>>>(xb, wqkv, (void*)qkv, SD);
    attn_kernel<<<960, 256, 0, stream>>>(qkv, qkv + BHSD, qkv + 2 * BHSD, Op, lp);
    norm_kernel<<<3072, 256, 0, stream>>>((const float4*)Op, lp, (uint64_t*)ao);
    gemm_bt<1><<<dim3(SD / 128, SM / 64), 256, 0, stream>>>(ao, wob, (void*)out, SD);
}